// Round 7
// baseline (18683.379 us; speedup 1.0000x reference)
//
#include <hip/hip_runtime.h>
#include <stdint.h>

#define TT    8192
#define EMBD  128
#define HID   256
#define G4    1024      // 4*HID
#define NTAGS 17
#define NBLK  16        // recurrence blocks; block b owns h[b*16 .. b*16+16)
#define SH    16        // HID / NBLK
#define QW    68        // padded LDS stride per k-quarter (conflict-free)

typedef unsigned int u32;

__device__ __forceinline__ float sigf(float x) { return 1.f / (1.f + __expf(-x)); }
__device__ __forceinline__ float tanhf_fast(float x) {
    x = fminf(15.f, fmaxf(-15.f, x));
    float a = __expf(2.f * x);
    return (a - 1.f) / (a + 1.f);
}

// ---------------------------------------------------------------------------
// Kernel A: xg[t][j] = dot(emb[tok[t]], W_ih[j]) + b_ih[j] + b_hh[j]
// ---------------------------------------------------------------------------
__global__ __launch_bounds__(256) void xg_kernel(
    const int* __restrict__ tok, const float* __restrict__ emb,
    const float* __restrict__ Wih, const float* __restrict__ bih,
    const float* __restrict__ bhh, float* __restrict__ xg)
{
    __shared__ __align__(16) float es[4][EMBD];
    const int tid = threadIdx.x;
    const int t0  = blockIdx.x * 4;

    for (int p = tid; p < 4 * EMBD; p += 256) {
        const int tt = p >> 7, k = p & 127;
        es[tt][k] = emb[(long)tok[t0 + tt] * EMBD + k];
    }
    __syncthreads();

#pragma unroll
    for (int q = 0; q < 4; ++q) {
        const int j = q * 256 + tid;
        const float4* wr = (const float4*)(Wih + (long)j * EMBD);
        float a0 = 0.f, a1 = 0.f, a2 = 0.f, a3 = 0.f;
#pragma unroll 8
        for (int k4 = 0; k4 < EMBD / 4; ++k4) {
            const float4 w  = wr[k4];
            const float4 e0 = ((const float4*)es[0])[k4];
            const float4 e1 = ((const float4*)es[1])[k4];
            const float4 e2 = ((const float4*)es[2])[k4];
            const float4 e3 = ((const float4*)es[3])[k4];
            a0 += w.x*e0.x + w.y*e0.y + w.z*e0.z + w.w*e0.w;
            a1 += w.x*e1.x + w.y*e1.y + w.z*e1.z + w.w*e1.w;
            a2 += w.x*e2.x + w.y*e2.y + w.z*e2.z + w.w*e2.w;
            a3 += w.x*e3.x + w.y*e3.y + w.z*e3.z + w.w*e3.w;
        }
        const float bb = bih[j] + bhh[j];
        xg[(long)(t0 + 0) * G4 + j] = a0 + bb;
        xg[(long)(t0 + 1) * G4 + j] = a1 + bb;
        xg[(long)(t0 + 2) * G4 + j] = a2 + bb;
        xg[(long)(t0 + 3) * G4 + j] = a3 + bb;
    }
}

// ---------------------------------------------------------------------------
// Kernel B: LSTM recurrence, exactly NBLK=16 blocks (co-residency trivial).
// Exchange protocol (R3-proven, placement-independent): producer packs
// ((s+1)<<16)|bf16(h) into one word, publishes with a relaxed AGENT-scope
// atomic store (serviced at the coherence point); each consumer thread
// polls its own word with relaxed agent atomic loads. Tag travels with the
// data -> no fences; tags in [1,8192] can never alias 0xAAAA poison.
//
// __launch_bounds__(256, 1): only 16 CUs are busy — occupancy is worthless,
// register budget is everything. Weights are 16 NAMED float4s with an asm
// pin; R3-R6's VGPR_Count=52..56 proved the compiler otherwise re-loads
// 64 KB/block of W_hh from L2 every step, on the serial critical path.
// ---------------------------------------------------------------------------
__global__ __launch_bounds__(256, 1) void lstm_kernel(
    const float* __restrict__ Whh, const float* __restrict__ xg,
    u32* __restrict__ hx)
{
    const int tid = threadIdx.x;
    const int b   = blockIdx.x;
    const int w   = tid >> 6;
    const int L   = tid & 63;
    const int g   = L >> 4;
    const int l15 = L & 15;
    const int hi  = l15 >> 2;
    const int q   = L & 3;
    const int row = g * HID + b * SH + w * 4 + hi;

    const float4* wsrc = (const float4*)(Whh + (long)row * HID + q * 64);
#define LOADW(J) float4 w##J = wsrc[J];
    LOADW(0)  LOADW(1)  LOADW(2)  LOADW(3)
    LOADW(4)  LOADW(5)  LOADW(6)  LOADW(7)
    LOADW(8)  LOADW(9)  LOADW(10) LOADW(11)
    LOADW(12) LOADW(13) LOADW(14) LOADW(15)
#undef LOADW
#define PINW(J) asm volatile("" : "+v"(w##J.x), "+v"(w##J.y), "+v"(w##J.z), "+v"(w##J.w));
    PINW(0)  PINW(1)  PINW(2)  PINW(3)
    PINW(4)  PINW(5)  PINW(6)  PINW(7)
    PINW(8)  PINW(9)  PINW(10) PINW(11)
    PINW(12) PINW(13) PINW(14) PINW(15)
#undef PINW

    __shared__ __align__(16) float hlds[2][4 * QW];
    for (int i = tid; i < 4 * QW; i += 256) hlds[0][i] = 0.f;   // h_0 = 0
    __syncthreads();

    float c_reg = 0.f;
    const bool leader = (g == 0) && (q == 0);      // lanes 0,4,8,12 per wave
    const int  gidx   = b * SH + w * 4 + hi;       // h index this leader owns
    const int  myslot = (tid >> 6) * QW + (tid & 63);
    const bool remote = (tid >> 4) != b;

    const float* xgp = xg + row;
    float xg0 = xgp[0];
    float xg1 = xgp[G4];               // may prefetch past xg end into hx: benign

#define ACC(J) { const float4 hv = *(const float4*)(hb + (J)*4); \
        p0 = __builtin_fmaf(w##J.x, hv.x, p0); \
        p1 = __builtin_fmaf(w##J.y, hv.y, p1); \
        p2 = __builtin_fmaf(w##J.z, hv.z, p2); \
        p3 = __builtin_fmaf(w##J.w, hv.w, p3); }

#define STEP(CUR, S_, XGV) { \
        const float* hb = &hlds[CUR][q * QW]; \
        float p0 = 0.f, p1 = 0.f, p2 = 0.f, p3 = 0.f; \
        ACC(0)  ACC(1)  ACC(2)  ACC(3)  ACC(4)  ACC(5)  ACC(6)  ACC(7) \
        ACC(8)  ACC(9)  ACC(10) ACC(11) ACC(12) ACC(13) ACC(14) ACC(15) \
        float p = (p0 + p1) + (p2 + p3); \
        p += __shfl_xor(p, 1, 64); \
        p += __shfl_xor(p, 2, 64); \
        const float pre = p + (XGV); \
        const float vf = __shfl(pre, 16 + l15, 64); \
        const float vg = __shfl(pre, 32 + l15, 64); \
        const float vo = __shfl(pre, 48 + l15, 64); \
        if (leader) { \
            const float i_ = sigf(pre); \
            const float f_ = sigf(vf); \
            const float g_ = tanhf_fast(vg); \
            const float o_ = sigf(vo); \
            c_reg = f_ * c_reg + i_ * g_; \
            const float hn = o_ * tanhf_fast(c_reg); \
            const u32 hb32 = __float_as_uint(hn); \
            const u32 rb   = (hb32 + 0x7FFFu + ((hb32 >> 16) & 1u)) >> 16; \
            const u32 word = ((u32)((S_) + 1) << 16) | rb; \
            __hip_atomic_store(&hx[(long)((S_) + 1) * HID + gidx], word, \
                               __ATOMIC_RELAXED, __HIP_MEMORY_SCOPE_AGENT); \
            hlds[(CUR) ^ 1][(gidx >> 6) * QW + (gidx & 63)] = \
                __uint_as_float(rb << 16); \
        } \
        if (remote) { \
            const u32 want = (u32)((S_) + 1) << 16; \
            u32* wp = &hx[(long)((S_) + 1) * HID + tid]; \
            u32 u; \
            do { u = __hip_atomic_load(wp, __ATOMIC_RELAXED, \
                                       __HIP_MEMORY_SCOPE_AGENT); } \
            while ((u & 0xFFFF0000u) != want); \
            hlds[(CUR) ^ 1][myslot] = __uint_as_float(u << 16); \
        } \
        __syncthreads(); }

    for (int s = 0; s < TT; s += 2) {
        const float xgn0 = xgp[(long)(s + 2) * G4];
        STEP(0, s, xg0)
        const float xgn1 = xgp[(long)(s + 3) * G4];
        STEP(1, s + 1, xg1)
        xg0 = xgn0; xg1 = xgn1;
    }
#undef STEP
#undef ACC
}

// ---------------------------------------------------------------------------
// Kernel C: tag logits + log_softmax; unpacks bf16 h from tagged words.
// ---------------------------------------------------------------------------
__global__ __launch_bounds__(64) void out_kernel(
    const u32* __restrict__ hx, const float* __restrict__ Wout,
    const float* __restrict__ bout, float* __restrict__ out)
{
    const int t   = blockIdx.x;
    const int tid = threadIdx.x;
    __shared__ __align__(16) float hs[HID];
    __shared__ float lg[NTAGS];

    const uint4 uu = ((const uint4*)(hx + (long)(t + 1) * HID))[tid];
    hs[tid * 4 + 0] = __uint_as_float(uu.x << 16);
    hs[tid * 4 + 1] = __uint_as_float(uu.y << 16);
    hs[tid * 4 + 2] = __uint_as_float(uu.z << 16);
    hs[tid * 4 + 3] = __uint_as_float(uu.w << 16);
    __syncthreads();

    if (tid < NTAGS) {
        const float4* wr = (const float4*)(Wout + (long)tid * HID);
        float p = 0.f;
#pragma unroll 8
        for (int qq = 0; qq < HID / 4; ++qq) {
            const float4 w = wr[qq];
            const float4 h = ((const float4*)hs)[qq];
            p += w.x*h.x + w.y*h.y + w.z*h.z + w.w*h.w;
        }
        lg[tid] = p + bout[tid];
    }
    __syncthreads();

    if (tid < NTAGS) {
        float m = -1e30f;
        for (int gg = 0; gg < NTAGS; ++gg) m = fmaxf(m, lg[gg]);
        float ss = 0.f;
        for (int gg = 0; gg < NTAGS; ++gg) ss += __expf(lg[gg] - m);
        out[(long)t * NTAGS + tid] = lg[tid] - (m + __logf(ss));
    }
}

// ---------------------------------------------------------------------------
// ws layout (total 41,944,064 B — well under the proven budget):
//   xg : 33,554,432 B
//   hx :  8,389,632 B   (8193 * 256 tagged words)
// ---------------------------------------------------------------------------
extern "C" void kernel_launch(void* const* d_in, const int* in_sizes, int n_in,
                              void* d_out, int out_size, void* d_ws, size_t ws_size,
                              hipStream_t stream)
{
    const int*   tok  = (const int*)  d_in[0];
    const float* emb  = (const float*)d_in[1];
    const float* Wih  = (const float*)d_in[2];
    const float* Whh  = (const float*)d_in[3];
    const float* bih  = (const float*)d_in[4];
    const float* bhh  = (const float*)d_in[5];
    const float* Wout = (const float*)d_in[6];
    const float* bout = (const float*)d_in[7];
    float* out = (float*)d_out;

    char* ws = (char*)d_ws;
    float* xg = (float*)(ws);
    u32*   hx = (u32*)  (ws + 33554432UL);

    xg_kernel  <<<TT / 4, 256, 0, stream>>>(tok, emb, Wih, bih, bhh, xg);
    lstm_kernel<<<NBLK,   256, 0, stream>>>(Whh, xg, hx);
    out_kernel <<<TT,     64,  0, stream>>>(hx, Wout, bout, out);
}